// Round 8
// baseline (10349.559 us; speedup 1.0000x reference)
//
#include <hip/hip_runtime.h>
#include <hip/hip_bf16.h>
#include <math.h>

// Problem constants
#define BB 64
#define TT 512
#define II 256
#define HH 512
#define GG 2048   // 4H
#define KP  520   // W_hh^T LDS row pad (bf16 elems)
#define XPAD 264  // x / W_ih row pad

typedef unsigned char u8;
typedef unsigned short u16;
typedef unsigned int u32;
typedef __attribute__((ext_vector_type(4))) int   i32x4;
typedef __attribute__((ext_vector_type(2))) int   i32x2;
typedef __attribute__((ext_vector_type(8))) short short8v;
typedef __attribute__((ext_vector_type(4))) float f32x4;

__device__ __forceinline__ u16 f2bf(float f) {
    unsigned u = __float_as_uint(f);
    unsigned r = (u + 0x7fff + ((u >> 16) & 1)) >> 16;  // RNE
    return (u16)r;
}
__device__ __forceinline__ float bf2f(u16 h) {
    return __uint_as_float(((unsigned)h) << 16);
}
__device__ __forceinline__ float sigf(float v) {
    return 1.f / (1.f + __expf(-v));
}
__device__ __forceinline__ float tanh_s(float v) {
    float a = fabsf(v);
    float e = __expf(2.f * a);
    float r = 1.f - 2.f / (e + 1.f);
    return copysignf(r, v);
}

// h load: 16B, L1+L2 bypass (device-coherent)
#define HLD(dst, base, OFF) \
    asm volatile("global_load_dwordx4 %0, %1, off offset:" OFF " sc0 sc1" \
                 : "=v"(dst) : "v"(base))
// x load: 16B, saddr + 32-bit voffset (plain caching; x streamed once)
#define XLD(dst, voff, sbase) \
    asm volatile("global_load_dwordx4 %0, %1, %2" \
                 : "=v"(dst) : "v"(voff), "s"(sbase))
// packed f32x2 -> bf16x2 (RNE, HW)
#define CVTPK(d, lo, hi) \
    asm("v_cvt_pk_bf16_f32 %0, %1, %2" : "=v"(d) : "v"(lo), "v"(hi))

__global__ void __launch_bounds__(64, 1) slstm_kernel(
    const float* __restrict__ x, const float* __restrict__ wih,
    const float* __restrict__ whh, const float* __restrict__ bias,
    float* __restrict__ out, u8* __restrict__ flagb,
    u16* __restrict__ hbuf /* [2 parity][2 hi/lo][BB][HH] bf16 */)
{
    __shared__ u16 lds_whh[4 * 16 * KP];    // W_hh^T slice (shared by chains) 66.6 KB
    __shared__ u16 lds_wih[64 * XPAD];      // W_ih^T slice (shared)           33.8 KB
    __shared__ u16 lds_x[4][16 * XPAD];     // x tile per chain                33.8 KB

    const int l  = threadIdx.x;             // lane (1 wave/block)
    const int js = blockIdx.x;              // h-col slice / producer id (0..31)
    const int j0 = js * 16;
    const int c  = l & 15, kq = l >> 4;

    // ---- W_hh^T slice -> LDS ----
    for (int q = 0; q < 4; ++q)
        for (int kk = 0; kk < 128; ++kk) {
            int k = kk * 4 + kq;
            lds_whh[(q * 16 + c) * KP + k] =
                f2bf(whh[(size_t)k * GG + q * 512 + j0 + c]);
        }
    // ---- W_ih^T slice -> LDS ----
    for (int q = 0; q < 4; ++q)
        for (int kk = 0; kk < 64; ++kk) {
            int k = kk * 4 + kq;
            lds_wih[(q * 16 + c) * XPAD + k] =
                f2bf(wih[(size_t)k * GG + q * 512 + j0 + c]);
        }

    float bq[4];
#pragma unroll
    for (int q = 0; q < 4; ++q) bq[q] = bias[q * 512 + j0 + c];
    float cst[4][4];
#pragma unroll
    for (int ct = 0; ct < 4; ++ct)
#pragma unroll
        for (int rg = 0; rg < 4; ++rg) cst[ct][rg] = 0.f;
    __syncthreads();

    f32x4 acc[4][4];   // [chain][gate] — all indices static (unrolled loops)

#define XPG(CT) do {                                                            \
    _Pragma("unroll") for (int q = 0; q < 4; ++q)                               \
        acc[CT][q] = (f32x4){bq[q], bq[q], bq[q], bq[q]};                       \
    _Pragma("unroll") for (int s = 0; s < 8; ++s) {                             \
        short8v a_ = *(const short8v*)&lds_x[CT][c * XPAD + 32 * s + 8 * kq];   \
        _Pragma("unroll") for (int q = 0; q < 4; ++q) {                         \
            short8v b_ = *(const short8v*)&lds_wih[(q * 16 + c) * XPAD + 32 * s + 8 * kq]; \
            acc[CT][q] = __builtin_amdgcn_mfma_f32_16x16x32_bf16(a_, b_, acc[CT][q], 0, 0, 0); \
        } } } while (0)

#define HMM(CT, S, FH, FL) do {                                                 \
        short8v ah_ = __builtin_bit_cast(short8v, FH);                          \
        short8v al_ = __builtin_bit_cast(short8v, FL);                          \
        _Pragma("unroll")                                                       \
        for (int q = 0; q < 4; ++q) {                                           \
            short8v b_ = *(const short8v*)&lds_whh[(q * 16 + c) * KP + 32 * (S) + 8 * kq]; \
            acc[CT][q] = __builtin_amdgcn_mfma_f32_16x16x32_bf16(ah_, b_, acc[CT][q], 0, 0, 0); \
            acc[CT][q] = __builtin_amdgcn_mfma_f32_16x16x32_bf16(al_, b_, acc[CT][q], 0, 0, 0); \
        }                                                                       \
    } while (0)

    // ---- prologue: per chain, x(0) -> regs -> lds_x[ct]; acc[ct] = xp(0) ----
    f32x4 xr[16];
#pragma unroll
    for (int ct = 0; ct < 4; ++ct) {
        const u32 vbase = (u32)(ct * 16 * TT * II * 4) + 16 * (u32)l;
#pragma unroll
        for (int r = 0; r < 16; ++r)
            XLD(xr[r], vbase + (u32)(r * TT * II * 4), x);
        asm volatile("s_waitcnt vmcnt(0)" ::: "memory");
        __builtin_amdgcn_sched_barrier(0);
#pragma unroll
        for (int r = 0; r < 16; ++r) {
            i32x2 p;
            CVTPK(p[0], xr[r][0], xr[r][1]);
            CVTPK(p[1], xr[r][2], xr[r][3]);
            *(i32x2*)&lds_x[ct][r * XPAD + 4 * l] = p;
        }
        XPG(ct);
    }

    for (int t = 0; t < TT; ++t) {
        const int have = (t > 0);
        const int rp = (t - 1) & 1;
        const int wp = t & 1;
        const int tn = (t + 1 < TT) ? t + 1 : TT - 1;

#pragma unroll
        for (int ct = 0; ct < 4; ++ct) {
            const int b0 = ct * 16;
            const u32 vbase = (u32)(b0 * TT * II * 4) + 16 * (u32)l;

            // ---- 1: poll the 32 producer flags of (ct, t-1) ----
            if (have) {
                const u8* fb = flagb + ((size_t)(ct * TT + (t - 1))) * 32;
                while (true) {
                    i32x4 w0, w1;
                    asm volatile(
                        "global_load_dwordx4 %0, %2, off sc0 sc1\n\t"
                        "global_load_dwordx4 %1, %2, off offset:16 sc0 sc1\n\t"
                        "s_waitcnt vmcnt(0)"
                        : "=v"(w0), "=v"(w1) : "v"(fb) : "memory");
                    int m = w0[0] & w0[1] & w0[2] & w0[3] &
                            w1[0] & w1[1] & w1[2] & w1[3];
                    if (m == 0x01010101) break;
                    __builtin_amdgcn_s_sleep(1);
                }
                __builtin_amdgcn_sched_barrier(0);
            }

            // ---- 2: issue 32 h loads (hi+lo A-fragments) ----
            i32x4 h0,h1,h2,h3,h4,h5,h6,h7,h8,h9,h10,h11,h12,h13,h14,h15;
            i32x4 g0,g1,g2,g3,g4,g5,g6,g7,g8,g9,g10,g11,g12,g13,g14,g15;
            const u16* hb = hbuf + (size_t)(rp * 2) * BB * HH
                            + (size_t)(b0 + c) * HH + 8 * kq;
            const u16* lb = hb + BB * HH;
            if (have) {
                HLD(h0, hb,   "0"); HLD(g0, lb,   "0");
                HLD(h1, hb,  "64"); HLD(g1, lb,  "64");
                HLD(h2, hb, "128"); HLD(g2, lb, "128");
                HLD(h3, hb, "192"); HLD(g3, lb, "192");
                HLD(h4, hb, "256"); HLD(g4, lb, "256");
                HLD(h5, hb, "320"); HLD(g5, lb, "320");
                HLD(h6, hb, "384"); HLD(g6, lb, "384");
                HLD(h7, hb, "448"); HLD(g7, lb, "448");
                HLD(h8, hb, "512"); HLD(g8, lb, "512");
                HLD(h9, hb, "576"); HLD(g9, lb, "576");
                HLD(h10,hb, "640"); HLD(g10,lb, "640");
                HLD(h11,hb, "704"); HLD(g11,lb, "704");
                HLD(h12,hb, "768"); HLD(g12,lb, "768");
                HLD(h13,hb, "832"); HLD(g13,lb, "832");
                HLD(h14,hb, "896"); HLD(g14,lb, "896");
                HLD(h15,hb, "960"); HLD(g15,lb, "960");
            }

            // ---- 3: issue first 8 x(t+1) loads ----
#pragma unroll
            for (int r = 0; r < 8; ++r)
                XLD(xr[r], vbase + (u32)(r * TT * II * 4 + tn * II * 4), x);

            // ---- 4/5: pipelined hh-GEMM (counted waits exact: 32h+8x) ----
            if (have) {
                asm volatile("s_waitcnt vmcnt(24)" ::: "memory"); // h0..15 done
                __builtin_amdgcn_sched_barrier(0);
                HMM(ct, 0, h0, g0); HMM(ct, 1, h1, g1);
                HMM(ct, 2, h2, g2); HMM(ct, 3, h3, g3);
                HMM(ct, 4, h4, g4); HMM(ct, 5, h5, g5);
                HMM(ct, 6, h6, g6); HMM(ct, 7, h7, g7);
                asm volatile("s_waitcnt vmcnt(8)" ::: "memory");  // all h done
                __builtin_amdgcn_sched_barrier(0);
            }
            // ---- 6: issue second 8 x(t+1) loads ----
#pragma unroll
            for (int r = 8; r < 16; ++r)
                XLD(xr[r], vbase + (u32)(r * TT * II * 4 + tn * II * 4), x);
            if (have) {
                HMM(ct, 8, h8, g8); HMM(ct, 9, h9, g9);
                HMM(ct,10,h10,g10); HMM(ct,11,h11,g11);
                HMM(ct,12,h12,g12); HMM(ct,13,h13,g13);
                HMM(ct,14,h14,g14); HMM(ct,15,h15,g15);
            }

            // ---- 7: epilogue: activations, c update, hbuf + out stores ----
            u16* hdst_hi = hbuf + (size_t)(wp * 2) * BB * HH;
            u16* hdst_lo = hdst_hi + BB * HH;
            const int j = j0 + c;
#pragma unroll
            for (int rg = 0; rg < 4; ++rg) {
                int b = b0 + kq * 4 + rg;
                float ig = sigf(acc[ct][0][rg]);
                float fg = sigf(acc[ct][1][rg]);
                float cg = tanh_s(acc[ct][2][rg]);
                float og = acc[ct][3][rg];        // reference: NO sigmoid on outgate
                float cy = fg * cst[ct][rg] + ig * cg;
                cst[ct][rg] = cy;
                float hy = og * tanh_s(cy) + og;  // hy = og*tanh(cy) + og (quirk)
                u16 hi = f2bf(hy);
                float lo = hy - bf2f(hi);
                __hip_atomic_store(&hdst_hi[(size_t)b * HH + j], hi,
                                   __ATOMIC_RELAXED, __HIP_MEMORY_SCOPE_AGENT);
                __hip_atomic_store(&hdst_lo[(size_t)b * HH + j], f2bf(lo),
                                   __ATOMIC_RELAXED, __HIP_MEMORY_SCOPE_AGENT);
                out[((size_t)b * TT + t) * HH + j] = hy;
            }

            // ---- 8: drain stores (x loads retired too), set flag ----
            asm volatile("s_waitcnt vmcnt(0)" ::: "memory");
            if (l == 0)
                __hip_atomic_store(flagb + ((size_t)(ct * TT + t)) * 32 + js, (u8)1,
                                   __ATOMIC_RELAXED, __HIP_MEMORY_SCOPE_AGENT);

            // ---- 9: x(t+1) -> lds_x[ct]; xp(t+1) -> acc[ct] (off critical path) ----
#pragma unroll
            for (int r = 0; r < 16; ++r) {
                i32x2 p;
                CVTPK(p[0], xr[r][0], xr[r][1]);
                CVTPK(p[1], xr[r][2], xr[r][3]);
                *(i32x2*)&lds_x[ct][r * XPAD + 4 * l] = p;
            }
            XPG(ct);
        }
    }
}

extern "C" void kernel_launch(void* const* d_in, const int* in_sizes, int n_in,
                              void* d_out, int out_size, void* d_ws, size_t ws_size,
                              hipStream_t stream) {
    const float* x    = (const float*)d_in[0];
    const float* wih  = (const float*)d_in[1];
    const float* whh  = (const float*)d_in[2];
    const float* bias = (const float*)d_in[3];
    float* out = (float*)d_out;

    // ws: [0,64KB) byte flags [4 chains][512 t][32 producers]; [64KB,+512KB) h ping-pong
    u8*  flagb = (u8*)d_ws;
    u16* hbuf  = (u16*)((char*)d_ws + 65536);
    hipMemsetAsync(d_ws, 0, 65536, stream);   // flags=0 each launch (t=0 reads no h)

    hipLaunchKernelGGL(slstm_kernel, dim3(32), dim3(64), 0, stream,
                       x, wih, whh, bias, out, flagb, hbuf);
}

// Round 9
// 2545.564 us; speedup vs baseline: 4.0657x; 4.0657x over previous
//
#include <hip/hip_runtime.h>
#include <hip/hip_bf16.h>
#include <math.h>

// Problem constants
#define BB 64
#define TT 512
#define II 256
#define HH 512
#define GG 2048   // 4H
#define NBLK 128  // 32 col-slices * 4 b-tiles
#define KP  520   // W_hh^T LDS row pad (bf16 elems)
#define XPAD 264  // x / W_ih row pad

typedef unsigned char u8;
typedef unsigned short u16;
typedef unsigned int u32;
typedef __attribute__((ext_vector_type(4))) int   i32x4;
typedef __attribute__((ext_vector_type(2))) int   i32x2;
typedef __attribute__((ext_vector_type(8))) short short8v;
typedef __attribute__((ext_vector_type(4))) float f32x4;

__device__ __forceinline__ u16 f2bf(float f) {
    unsigned u = __float_as_uint(f);
    unsigned r = (u + 0x7fff + ((u >> 16) & 1)) >> 16;  // RNE
    return (u16)r;
}
__device__ __forceinline__ float bf2f(u16 h) {
    return __uint_as_float(((unsigned)h) << 16);
}
__device__ __forceinline__ float sigf(float v) {
    return 1.f / (1.f + __expf(-v));
}
__device__ __forceinline__ float tanh_s(float v) {
    float a = fabsf(v);
    float e = __expf(2.f * a);
    float r = 1.f - 2.f / (e + 1.f);
    return copysignf(r, v);
}

// h load: 16B, L1+L2 bypass (coherent at MALL)
#define HLD(dst, base, OFF) \
    asm volatile("global_load_dwordx4 %0, %1, off offset:" OFF " sc0 sc1" \
                 : "=v"(dst) : "v"(base))
// x load: 16B, saddr + 32-bit voffset (plain caching; x is streamed once)
#define XLD(dst, voff, sbase) \
    asm volatile("global_load_dwordx4 %0, %1, %2" \
                 : "=v"(dst) : "v"(voff), "s"(sbase))
// packed f32x2 -> bf16x2 (RNE, HW)
#define CVTPK(d, lo, hi) \
    asm("v_cvt_pk_bf16_f32 %0, %1, %2" : "=v"(d) : "v"(lo), "v"(hi))

__global__ void __launch_bounds__(64, 1) slstm_kernel(
    const float* __restrict__ x, const float* __restrict__ wih,
    const float* __restrict__ whh, const float* __restrict__ bias,
    float* __restrict__ out, u8* __restrict__ flagb,
    u16* __restrict__ hbuf /* [2 parity][2 hi/lo][BB][HH] bf16 */)
{
    __shared__ u16 lds_whh[4 * 16 * KP];   // W_hh^T slice  66.6 KB
    __shared__ u16 lds_wih[64 * XPAD];     // W_ih^T slice  33.8 KB
    __shared__ u16 lds_x[16 * XPAD];       // x tile         8.4 KB

    const int l  = threadIdx.x;            // lane (1 wave/block)
    const int bt = blockIdx.x & 3;         // b-tile -> independent chain
    const int js = blockIdx.x >> 2;        // h-col slice (producer id)
    const int b0 = bt * 16, j0 = js * 16;
    const int c  = l & 15, kq = l >> 4;

    // ---- W_hh^T slice -> LDS ----
    for (int q = 0; q < 4; ++q)
        for (int kk = 0; kk < 128; ++kk) {
            int k = kk * 4 + kq;
            lds_whh[(q * 16 + c) * KP + k] =
                f2bf(whh[(size_t)k * GG + q * 512 + j0 + c]);
        }
    // ---- W_ih^T slice -> LDS ----
    for (int q = 0; q < 4; ++q)
        for (int kk = 0; kk < 64; ++kk) {
            int k = kk * 4 + kq;
            lds_wih[(q * 16 + c) * XPAD + k] =
                f2bf(wih[(size_t)k * GG + q * 512 + j0 + c]);
        }

    float bq[4];
#pragma unroll
    for (int q = 0; q < 4; ++q) bq[q] = bias[q * 512 + j0 + c];

    float cst[4] = {0.f, 0.f, 0.f, 0.f};
    __syncthreads();   // weights staged (single wave: cheap)

    // ---- x addressing: saddr = x, voff[r] = ((b0+r)*TT + t)*II*4 + 16*l ----
    const u32 vbase = (u32)(b0 * TT * II * 4) + 16 * (u32)l;

    // ---- prologue: x(0) -> regs -> lds_x ----
    f32x4 xr[16];
#pragma unroll
    for (int r = 0; r < 16; ++r) {
        u32 vo = vbase + (u32)(r * TT * II * 4);   // t=0
        XLD(xr[r], vo, x);
    }
    asm volatile("s_waitcnt vmcnt(0)" ::: "memory");
    __builtin_amdgcn_sched_barrier(0);
#pragma unroll
    for (int r = 0; r < 16; ++r) {
        i32x2 p;
        CVTPK(p[0], xr[r][0], xr[r][1]);
        CVTPK(p[1], xr[r][2], xr[r][3]);
        *(i32x2*)&lds_x[r * XPAD + 4 * l] = p;
    }

    for (int t = 0; t < TT; ++t) {
        // ---- A: issue flag loads for h_{t-1} (oldest in vmcnt order) ----
        i32x4 w0, w1;
        const u8* fb = flagb;
        if (t > 0) {
            fb = flagb + ((size_t)(bt * TT + (t - 1))) * 32;
            asm volatile(
                "global_load_dwordx4 %0, %2, off sc0 sc1\n\t"
                "global_load_dwordx4 %1, %2, off offset:16 sc0 sc1"
                : "=v"(w0), "=v"(w1) : "v"(fb) : "memory");
        }

        // ---- B: issue x(t+1) prefetch (16 loads; convert/write at step end) ----
        const int tn = (t + 1 < TT) ? t + 1 : TT - 1;
#pragma unroll
        for (int r = 0; r < 16; ++r) {
            u32 vo = vbase + (u32)(r * TT * II * 4) + (u32)(tn * II * 4);
            XLD(xr[r], vo, x);
        }

        // ---- C: xp = bias + x @ W_ih (no vmem; hides flag RTT) ----
        f32x4 acc[4];
#pragma unroll
        for (int q = 0; q < 4; ++q) acc[q] = (f32x4){bq[q], bq[q], bq[q], bq[q]};
#pragma unroll
        for (int s = 0; s < 8; ++s) {
            short8v a = *(const short8v*)&lds_x[c * XPAD + 32 * s + 8 * kq];
#pragma unroll
            for (int q = 0; q < 4; ++q) {
                short8v b = *(const short8v*)&lds_wih[(q * 16 + c) * XPAD + 32 * s + 8 * kq];
                acc[q] = __builtin_amdgcn_mfma_f32_16x16x32_bf16(a, b, acc[q], 0, 0, 0);
            }
        }

        // ---- D: confirm flags (2 flags oldest + 16 x -> wait 16). HOT SPIN:
        //      no s_sleep (keeps CU issuing -> no DPM down-clock; detect = RTT) ----
        if (t > 0) {
            asm volatile("s_waitcnt vmcnt(16)" ::: "memory");
            __builtin_amdgcn_sched_barrier(0);
            int m = w0[0] & w0[1] & w0[2] & w0[3] & w1[0] & w1[1] & w1[2] & w1[3];
            while (m != 0x01010101) {
                asm volatile(
                    "global_load_dwordx4 %0, %2, off sc0 sc1\n\t"
                    "global_load_dwordx4 %1, %2, off offset:16 sc0 sc1\n\t"
                    "s_waitcnt vmcnt(0)"
                    : "=v"(w0), "=v"(w1) : "v"(fb) : "memory");
                m = w0[0] & w0[1] & w0[2] & w0[3] & w1[0] & w1[1] & w1[2] & w1[3];
            }
            __builtin_amdgcn_sched_barrier(0);
        }

        // ---- E: h_{t-1} -> A-fragments (32x16B MALL loads), pipelined MFMA ----
        const int rp = (t - 1) & 1;   // t=0 -> parity 1 (never read: HMM skipped? no—
                                      //  t=0 reads zeros path kept identical to R4:
                                      //  hbuf parity-1 is never written before t=0 read,
                                      //  but t=0 skips nothing in R4; flags gate t>0 only.
                                      //  R4 read parity-1 at t=0 -> must be zero. Keep
                                      //  the memset covering hbuf parity-1 (see launch).
        const u16* hb = hbuf + (size_t)(rp * 2) * BB * HH + (size_t)(b0 + c) * HH + 8 * kq;
        const u16* lb = hb + BB * HH;  // lo plane
        i32x4 h0,h1,h2,h3,h4,h5,h6,h7,h8,h9,h10,h11,h12,h13,h14,h15;
        i32x4 g0,g1,g2,g3,g4,g5,g6,g7,g8,g9,g10,g11,g12,g13,g14,g15;
        HLD(h0, hb,   "0"); HLD(g0, lb,   "0");
        HLD(h1, hb,  "64"); HLD(g1, lb,  "64");
        HLD(h2, hb, "128"); HLD(g2, lb, "128");
        HLD(h3, hb, "192"); HLD(g3, lb, "192");
        HLD(h4, hb, "256"); HLD(g4, lb, "256");
        HLD(h5, hb, "320"); HLD(g5, lb, "320");
        HLD(h6, hb, "384"); HLD(g6, lb, "384");
        HLD(h7, hb, "448"); HLD(g7, lb, "448");
        HLD(h8, hb, "512"); HLD(g8, lb, "512");
        HLD(h9, hb, "576"); HLD(g9, lb, "576");
        HLD(h10,hb, "640"); HLD(g10,lb, "640");
        HLD(h11,hb, "704"); HLD(g11,lb, "704");
        HLD(h12,hb, "768"); HLD(g12,lb, "768");
        HLD(h13,hb, "832"); HLD(g13,lb, "832");
        HLD(h14,hb, "896"); HLD(g14,lb, "896");
        HLD(h15,hb, "960"); HLD(g15,lb, "960");

#define HMM(S, FH, FL) do {                                                     \
        short8v ah_ = __builtin_bit_cast(short8v, FH);                          \
        short8v al_ = __builtin_bit_cast(short8v, FL);                          \
        _Pragma("unroll")                                                       \
        for (int q = 0; q < 4; ++q) {                                           \
            short8v b_ = *(const short8v*)&lds_whh[(q * 16 + c) * KP + 32 * (S) + 8 * kq]; \
            acc[q] = __builtin_amdgcn_mfma_f32_16x16x32_bf16(ah_, b_, acc[q], 0, 0, 0); \
            acc[q] = __builtin_amdgcn_mfma_f32_16x16x32_bf16(al_, b_, acc[q], 0, 0, 0); \
        }                                                                       \
    } while (0)

        // first half: wait until <=16 outstanding (x retired or in flight; h oldest)
        asm volatile("s_waitcnt vmcnt(16)" ::: "memory");
        __builtin_amdgcn_sched_barrier(0);
        HMM(0, h0, g0); HMM(1, h1, g1); HMM(2, h2, g2); HMM(3, h3, g3);
        HMM(4, h4, g4); HMM(5, h5, g5); HMM(6, h6, g6); HMM(7, h7, g7);
        asm volatile("s_waitcnt vmcnt(0)" ::: "memory");
        __builtin_amdgcn_sched_barrier(0);
        HMM(8, h8, g8); HMM(9, h9, g9); HMM(10,h10,g10); HMM(11,h11,g11);
        HMM(12,h12,g12); HMM(13,h13,g13); HMM(14,h14,g14); HMM(15,h15,g15);

        // ---- F: epilogue ----
        const int wp = t & 1;
        u16* hdst_hi = hbuf + (size_t)(wp * 2) * BB * HH;
        u16* hdst_lo = hdst_hi + BB * HH;
        const int j = j0 + c;
#pragma unroll
        for (int rg = 0; rg < 4; ++rg) {
            int b = b0 + kq * 4 + rg;
            float ig = sigf(acc[0][rg]);
            float fg = sigf(acc[1][rg]);
            float cg = tanh_s(acc[2][rg]);
            float og = acc[3][rg];            // reference: NO sigmoid on outgate
            float cy = fg * cst[rg] + ig * cg;
            cst[rg] = cy;
            float hy = og * tanh_s(cy) + og;  // hy = og*tanh(cy) + og (reference quirk)
            out[((size_t)b * TT + t) * HH + j] = hy;
            u16 hi = f2bf(hy);
            float lo = hy - bf2f(hi);
            __hip_atomic_store(&hdst_hi[(size_t)b * HH + j], hi,
                               __ATOMIC_RELAXED, __HIP_MEMORY_SCOPE_AGENT);
            __hip_atomic_store(&hdst_lo[(size_t)b * HH + j], f2bf(lo),
                               __ATOMIC_RELAXED, __HIP_MEMORY_SCOPE_AGENT);
        }

        // ---- G: x(t+1) regs -> lds_x (overlaps store drain; loads long done) ----
#pragma unroll
        for (int r = 0; r < 16; ++r) {
            i32x2 p;
            CVTPK(p[0], xr[r][0], xr[r][1]);
            CVTPK(p[1], xr[r][2], xr[r][3]);
            *(i32x2*)&lds_x[r * XPAD + 4 * l] = p;
        }

        // ---- H: drain h/out stores to coherence point, then set flag ----
        asm volatile("s_waitcnt vmcnt(0)" ::: "memory");
        if (l == 0)
            __hip_atomic_store(flagb + ((size_t)(bt * TT + t)) * 32 + js, (u8)1,
                               __ATOMIC_RELAXED, __HIP_MEMORY_SCOPE_AGENT);
    }
}

extern "C" void kernel_launch(void* const* d_in, const int* in_sizes, int n_in,
                              void* d_out, int out_size, void* d_ws, size_t ws_size,
                              hipStream_t stream) {
    const float* x    = (const float*)d_in[0];
    const float* wih  = (const float*)d_in[1];
    const float* whh  = (const float*)d_in[2];
    const float* bias = (const float*)d_in[3];
    float* out = (float*)d_out;

    // ws: [0,64KB) byte flags [4 chains][512 t][32 producers]; [64KB,+512KB) h ping-pong
    u8*  flagb = (u8*)d_ws;
    u16* hbuf  = (u16*)((char*)d_ws + 65536);
    size_t clear = 65536 + (size_t)2 * 2 * BB * HH * sizeof(u16);
    hipMemsetAsync(d_ws, 0, clear, stream);   // flags=0, h_{-1}=0 (every call)

    hipLaunchKernelGGL(slstm_kernel, dim3(NBLK), dim3(64), 0, stream,
                       x, wih, whh, bias, out, flagb, hbuf);
}